// Round 9
// baseline (936.441 us; speedup 1.0000x reference)
//
#include <hip/hip_runtime.h>
#include <hip/hip_bf16.h>
#include <stdint.h>

// MoE FFN: sigmoid router (group-limited greedy top-8 of 64), SwiGLU experts
// (1024->512->1024) + shared expert (1024->2048->1024). All inputs fp32.
// R12: component-wise best-of. (a) GEMM restored to R7's proven 122us form:
// bf16 weights, pure gl2lds staging (A+B), 3-slot ring, counted vmcnt(4),
// FUSED tile 128x64 / nonfused 128x128, 3 blocks/CU. (b) transpose prepass
// rebuilt: old kernel was LDS-instr bound (16 scalar ds_read + 16 f2bf per
// thread, ~1.8 TB/s, ~230us total); new kernel does per-thread 4x4 register
// transpose (4 float4 loads -> 8 v_cvt_pk_bf16_f32 -> 4 ds_write_b64, LP=68)
// + 4 ds_read_b64 + 2x16B stores -> BW-bound (~130us predicted).
// Worklist balancing (R6) + combine-not-atomics (R5) kept.

#define S_TOK 4096
#define C_DIM 1024
#define E_NUM 64
#define H_DIM 512
#define HS_DIM 2048
#define ROWS_TOTAL (S_TOK * 8)
#define T_TILES 320   // ROWS_TOTAL/128 + E_NUM upper bound on routed m-tiles

typedef __attribute__((ext_vector_type(8))) short short8;
typedef __attribute__((ext_vector_type(4))) float f32x4;
typedef __attribute__((ext_vector_type(2))) unsigned int uint2v;

static __device__ __forceinline__ unsigned short f2bf(float f) {
    union { float f; uint32_t u; } v; v.f = f;
    uint32_t u = v.u;
    u += 0x7fffu + ((u >> 16) & 1u);   // RNE
    return (unsigned short)(u >> 16);
}

static __device__ __forceinline__ uint32_t cvtpk(float a, float b) {
    uint32_t r;
    asm("v_cvt_pk_bf16_f32 %0, %1, %2" : "=v"(r) : "v"(a), "v"(b));
    return r;
}

static __device__ __forceinline__ void gl2lds16(const void* g, void* l) {
    __builtin_amdgcn_global_load_lds(
        (const __attribute__((address_space(1))) uint32_t*)g,
        (__attribute__((address_space(3))) uint32_t*)l, 16, 0, 0);
}

// ---------------- router part 1: scores = sigmoid(x @ rw^T), fp32 ----------------
__global__ __launch_bounds__(256)
void router_scores_k(const float* __restrict__ x, const float* __restrict__ rw,
                     float* __restrict__ scores, int* __restrict__ counts) {
    if (blockIdx.x == 0 && threadIdx.x < E_NUM) counts[threadIdx.x] = 0;
    int t0 = blockIdx.x * 32;
    __shared__ float xs[32][36];
    __shared__ float wsm[64][36];
    int t = threadIdx.x;
    int tx = t & 15, ty = t >> 4;
    float acc[2][4] = {};
    for (int k0 = 0; k0 < C_DIM; k0 += 32) {
        {
            int r = t >> 3, c = t & 7;
            *(float4*)&xs[r][c * 4] = *(const float4*)(x + (size_t)(t0 + r) * C_DIM + k0 + c * 4);
        }
        #pragma unroll
        for (int i = 0; i < 2; i++) {
            int idx = t + 256 * i;
            int r = idx >> 3, c = idx & 7;
            *(float4*)&wsm[r][c * 4] = *(const float4*)(rw + (size_t)r * C_DIM + k0 + c * 4);
        }
        __syncthreads();
        #pragma unroll
        for (int kk = 0; kk < 32; kk += 4) {
            float4 a0 = *(const float4*)&xs[ty * 2 + 0][kk];
            float4 a1 = *(const float4*)&xs[ty * 2 + 1][kk];
            #pragma unroll
            for (int j = 0; j < 4; j++) {
                float4 b = *(const float4*)&wsm[tx * 4 + j][kk];
                acc[0][j] += a0.x * b.x + a0.y * b.y + a0.z * b.z + a0.w * b.w;
                acc[1][j] += a1.x * b.x + a1.y * b.y + a1.z * b.z + a1.w * b.w;
            }
        }
        __syncthreads();
    }
    #pragma unroll
    for (int i = 0; i < 2; i++)
        #pragma unroll
        for (int j = 0; j < 4; j++)
            scores[(size_t)(t0 + ty * 2 + i) * E_NUM + tx * 4 + j] =
                1.f / (1.f + __expf(-acc[i][j]));
}

// ---------------- router part 2: wave-parallel grouped top-k ----------------
__global__ __launch_bounds__(256)
void topk_k(const float* __restrict__ scores, const float* __restrict__ ebias,
            int* __restrict__ topk_idx, float* __restrict__ topk_w,
            int* __restrict__ counts) {
    int t = blockIdx.x * 4 + (threadIdx.x >> 6);
    int e = threadIdx.x & 63;
    float sc = scores[(size_t)t * E_NUM + e];
    float sb = sc + ebias[e];
    float m1 = sb, m2 = -1e30f;
    #pragma unroll
    for (int off = 1; off <= 4; off <<= 1) {
        float o1 = __shfl_xor(m1, off);
        float o2 = __shfl_xor(m2, off);
        float hi = fmaxf(m1, o1), lo = fminf(m1, o1);
        m2 = fmaxf(lo, fmaxf(m2, o2));
        m1 = hi;
    }
    float grp = m1 + m2;
    float grpv[8];
    #pragma unroll
    for (int g = 0; g < 8; g++) grpv[g] = __shfl(grp, g * 8);
    unsigned gsel = 0;
    #pragma unroll
    for (int k = 0; k < 4; k++) {
        float best = -1e30f; int bi = 0;
        #pragma unroll
        for (int g = 0; g < 8; g++)
            if (!((gsel >> g) & 1) && grpv[g] > best) { best = grpv[g]; bi = g; }
        gsel |= 1u << bi;
    }
    float val = ((gsel >> (e >> 3)) & 1) ? sb : -1e30f;
    int idx[8]; float sv[8]; float wsum = 0.f;
    #pragma unroll
    for (int k = 0; k < 8; k++) {
        uint32_t u = __float_as_uint(val);
        uint32_t mu = (u & 0x80000000u) ? ~u : (u | 0x80000000u);
        unsigned long long key = ((unsigned long long)mu << 6) | (unsigned long long)(63 - e);
        #pragma unroll
        for (int off = 32; off; off >>= 1) {
            unsigned long long ok = __shfl_xor(key, off);
            if (ok > key) key = ok;
        }
        int win = 63 - (int)(key & 63ull);
        idx[k] = win;
        sv[k] = __shfl(sc, win);
        wsum += sv[k];
        if (e == win) val = -1e30f;
    }
    float inv = 1.f / (wsum + 1e-20f);
    if (e < 8) {
        topk_idx[t * 8 + e] = idx[e];
        topk_w[t * 8 + e] = sv[e] * inv;
        atomicAdd(&counts[idx[e]], 1);
    }
}

// exclusive scan over 64 expert counts + m-tile worklist build, one wave
__global__ void scan_k(const int* __restrict__ counts, int* __restrict__ base,
                       int* __restrict__ cursor, int* __restrict__ tile_e,
                       int* __restrict__ tile_m0) {
    int e = threadIdx.x;
    int c = counts[e];
    int s = c;
    #pragma unroll
    for (int off = 1; off < 64; off <<= 1) {
        int o = __shfl_up(s, off);
        if (e >= off) s += o;
    }
    int ex = s - c;
    base[e] = ex;
    cursor[e] = ex;
    int nt = (c + 127) >> 7;
    int ts = nt;
    #pragma unroll
    for (int off = 1; off < 64; off <<= 1) {
        int o = __shfl_up(ts, off);
        if (e >= off) ts += o;
    }
    int tb = ts - nt;
    for (int i = 0; i < nt; i++) { tile_e[tb + i] = e; tile_m0[tb + i] = i * 128; }
    int total = __shfl(ts, 63);
    for (int j = total + e; j < T_TILES; j += 64) tile_e[j] = -1;
}

__global__ void scatter_k(const int* __restrict__ topk_idx, const float* __restrict__ topk_w,
                          int* __restrict__ cursor, int* __restrict__ row_token,
                          float* __restrict__ row_wgt, int* __restrict__ pos_of) {
    int i = blockIdx.x * blockDim.x + threadIdx.x;
    int e = topk_idx[i];
    int pos = atomicAdd(&cursor[e], 1);
    row_token[pos] = i >> 3;
    row_wgt[pos] = topk_w[i];
    pos_of[i] = pos;
}

// ---------------- combine: out[t] += sum_k O[pos_of[t*8+k]] (weights pre-applied) ---
__global__ __launch_bounds__(256)
void combine_k(const float* __restrict__ O, const int* __restrict__ pos_of,
               float* __restrict__ out) {
    int t = blockIdx.x;
    int c = threadIdx.x;
    float4 s = ((const float4*)(out + (size_t)t * C_DIM))[c];
    int p[8];
    #pragma unroll
    for (int k = 0; k < 8; k++) p[k] = pos_of[t * 8 + k];
    #pragma unroll
    for (int k = 0; k < 8; k++) {
        float4 v = ((const float4*)(O + (size_t)p[k] * C_DIM))[c];
        s.x += v.x; s.y += v.y; s.z += v.z; s.w += v.w;
    }
    ((float4*)(out + (size_t)t * C_DIM))[c] = s;
}

// ---------------- prepass: fp32 -> bf16 elementwise (x) ----------------
__global__ void cvt_bf16_k(const float* __restrict__ in, unsigned short* __restrict__ out, int n8) {
    int i = blockIdx.x * blockDim.x + threadIdx.x;
    if (i >= n8) return;
    float4 v0 = ((const float4*)in)[2 * i];
    float4 v1 = ((const float4*)in)[2 * i + 1];
    unsigned short t[8] = { f2bf(v0.x), f2bf(v0.y), f2bf(v0.z), f2bf(v0.w),
                            f2bf(v1.x), f2bf(v1.y), f2bf(v1.z), f2bf(v1.w) };
    ((uint4*)out)[i] = *(uint4*)t;
}

// ---------------- prepass: fp32 [R][C] -> bf16 [C][R], batched over z ----------------
// 64x64 tile/block. Per thread: 4x4 register-block transpose (4 float4 loads,
// 8 cvt_pk, 4 ds_write_b64), then 4 ds_read_b64 + 2x16B coalesced stores.
// LP=68 pad: writes 4-way (cheap), reads 2-way (free).
#define LP 68
__global__ __launch_bounds__(256)
void transpose_k(const float* __restrict__ in, unsigned short* __restrict__ out, int R, int C) {
    size_t bofs = (size_t)blockIdx.z * R * C;
    in += bofs; out += bofs;
    int r0 = blockIdx.y * 64, c0 = blockIdx.x * 64;
    __shared__ unsigned short T[64 * LP];
    int t = threadIdx.x;
    int cg = t & 15, rg = t >> 4;
    const float* ip = in + (size_t)(r0 + rg * 4) * C + c0 + cg * 4;
    float4 m0 = *(const float4*)(ip);
    float4 m1 = *(const float4*)(ip + C);
    float4 m2 = *(const float4*)(ip + 2 * C);
    float4 m3 = *(const float4*)(ip + 3 * C);
    // output rows c0+cg*4+j hold source col j; shorts ordered r, r+1, r+2, r+3
    uint2v wv;
    unsigned short* tb = &T[(cg * 4) * LP + rg * 4];
    wv[0] = cvtpk(m0.x, m1.x); wv[1] = cvtpk(m2.x, m3.x); *(uint2v*)(tb)          = wv;
    wv[0] = cvtpk(m0.y, m1.y); wv[1] = cvtpk(m2.y, m3.y); *(uint2v*)(tb + LP)     = wv;
    wv[0] = cvtpk(m0.z, m1.z); wv[1] = cvtpk(m2.z, m3.z); *(uint2v*)(tb + 2 * LP) = wv;
    wv[0] = cvtpk(m0.w, m1.w); wv[1] = cvtpk(m2.w, m3.w); *(uint2v*)(tb + 3 * LP) = wv;
    __syncthreads();
    int n = t >> 2, q = t & 3;
    const unsigned short* rb = &T[n * LP + q * 16];
    uint2v a0 = *(const uint2v*)(rb);
    uint2v a1 = *(const uint2v*)(rb + 4);
    uint2v a2 = *(const uint2v*)(rb + 8);
    uint2v a3 = *(const uint2v*)(rb + 12);
    unsigned short* op = out + (size_t)(c0 + n) * R + r0 + q * 16;
    uint4 s0, s1;
    s0.x = a0[0]; s0.y = a0[1]; s0.z = a1[0]; s0.w = a1[1];
    s1.x = a2[0]; s1.y = a2[1]; s1.z = a3[0]; s1.w = a3[1];
    *(uint4*)op = s0;
    *(uint4*)(op + 8) = s1;
}

// ---------------- GEMM: C[M,N] = A[M,K] @ Bt[N,K]^T, bf16 in, fp32 acc ----------------
// FUSED: tile 128x64 (wave 64x32, acc1+acc2 = 64 regs, LDS 48 KB, 3 blocks/CU)
// non-FUSED: tile 128x128 (wave 64x64, acc 64 regs, LDS 48 KB, 3 blocks/CU)
// 3-slot LDS ring, 2-deep prefetch, counted vmcnt(4) + raw barriers.
// EPI: 0 = SwiGLU(acc1)*acc2 -> bf16; 1 = f32 store; 2 = f32 scaled store
template<bool FUSED, bool GATHER, bool WL, int EPI>
__global__ __launch_bounds__(256, 3)
void gemm2_k(const short* __restrict__ A, const short* __restrict__ B1t,
             const short* __restrict__ B2t, void* __restrict__ Cout,
             int M, int N, int K,
             const int* __restrict__ counts, const int* __restrict__ base,
             const int* __restrict__ row_token, const float* __restrict__ row_wgt,
             const int* __restrict__ tile_e, const int* __restrict__ tile_m0) {
    constexpr int BN = FUSED ? 64 : 128;
    constexpr int NJ = FUSED ? 2 : 4;

    int e = 0, m0, Mrows, rowbase = 0;
    if (WL) {
        e = tile_e[blockIdx.y];
        if (e < 0) return;
        m0 = tile_m0[blockIdx.y];
        Mrows = counts[e];
        rowbase = base[e];
    } else {
        m0 = blockIdx.y * 128;
        Mrows = M;
    }
    int n0 = blockIdx.x * BN;
    const short* B1 = B1t + (WL ? (size_t)e * N * K : 0) + (size_t)n0 * K;
    const short* B2 = FUSED ? (B2t + (WL ? (size_t)e * N * K : 0) + (size_t)n0 * K) : nullptr;

    __shared__ short As[3 * 4096];                       // 3 x 128x32
    __shared__ short Bs1[FUSED ? 3 * 2048 : 3 * 4096];   // 3 x BNx32
    __shared__ short Bs2[FUSED ? 3 * 2048 : 16];

    int tid = threadIdx.x;
    int lane = tid & 63, w = tid >> 6;
    int wr = w >> 1, wc = w & 1;
    int quad = lane >> 4, l16 = lane & 15;
    int sr = lane >> 2, sc = lane & 3;

    const short* aptr[2];
    const short* b1ptr[2];
    const short* b2ptr;
    #pragma unroll
    for (int i = 0; i < 2; i++) {
        int row = w * 32 + i * 16 + sr;
        int mrow = m0 + row;
        int cl = mrow < Mrows ? mrow : (Mrows - 1);
        size_t arow;
        if (GATHER)  arow = (size_t)row_token[rowbase + cl];
        else if (WL) arow = (size_t)(rowbase + cl);
        else         arow = (size_t)mrow;
        aptr[i] = A + arow * K + sc * 8;
    }
    if constexpr (FUSED) {
        int row = w * 16 + sr;                 // 4 waves cover 64 B-rows
        b1ptr[0] = B1 + (size_t)row * K + sc * 8;
        b2ptr    = B2 + (size_t)row * K + sc * 8;
    } else {
        #pragma unroll
        for (int i = 0; i < 2; i++) {
            int row = w * 32 + i * 16 + sr;
            b1ptr[i] = B1 + (size_t)row * K + sc * 8;
        }
        b2ptr = nullptr;
    }

    f32x4 acc1[4][NJ] = {};
    f32x4 acc2[FUSED ? 4 : 1][NJ] = {};

    const int nk = K >> 5;
    auto stage = [&](int slot) {
        #pragma unroll
        for (int i = 0; i < 2; i++) {
            gl2lds16(aptr[i], &As[slot * 4096 + (w * 32 + i * 16) * 32]);
            aptr[i] += 32;
        }
        if constexpr (FUSED) {
            gl2lds16(b1ptr[0], &Bs1[slot * 2048 + w * 512]); b1ptr[0] += 32;
            gl2lds16(b2ptr,    &Bs2[slot * 2048 + w * 512]); b2ptr += 32;
        } else {
            #pragma unroll
            for (int i = 0; i < 2; i++) {
                gl2lds16(b1ptr[i], &Bs1[slot * 4096 + (w * 32 + i * 16) * 32]);
                b1ptr[i] += 32;
            }
        }
    };
    stage(0);
    if (nk > 1) stage(1);

    int slot = 0, nslot = 2;
    for (int t = 0; t < nk; t++) {
        // wait for stage t only: leave the 1 in-flight stage (4 loads/wave) pending
        if (t + 1 < nk) {
            asm volatile("s_waitcnt vmcnt(4)" ::: "memory");
        } else {
            asm volatile("s_waitcnt vmcnt(0)" ::: "memory");
        }
        __builtin_amdgcn_s_barrier();
        __builtin_amdgcn_sched_barrier(0);   // nothing crosses the barrier (rule #18)

        if (t + 2 < nk) stage(nslot);

        short8 a[4], b1[NJ], b2[NJ];
        #pragma unroll
        for (int i = 0; i < 4; i++)
            a[i] = *(const short8*)&As[slot * 4096 + (wr * 64 + i * 16 + l16) * 32 + quad * 8];
        if constexpr (FUSED) {
            #pragma unroll
            for (int j = 0; j < NJ; j++) {
                b1[j] = *(const short8*)&Bs1[slot * 2048 + (wc * 32 + j * 16 + l16) * 32 + quad * 8];
                b2[j] = *(const short8*)&Bs2[slot * 2048 + (wc * 32 + j * 16 + l16) * 32 + quad * 8];
            }
        } else {
            #pragma unroll
            for (int j = 0; j < NJ; j++)
                b1[j] = *(const short8*)&Bs1[slot * 4096 + (wc * 64 + j * 16 + l16) * 32 + quad * 8];
        }
        #pragma unroll
        for (int i = 0; i < 4; i++)
            #pragma unroll
            for (int j = 0; j < NJ; j++) {
                acc1[i][j] = __builtin_amdgcn_mfma_f32_16x16x32_bf16(a[i], b1[j], acc1[i][j], 0, 0, 0);
                if (FUSED)
                    acc2[i][j] = __builtin_amdgcn_mfma_f32_16x16x32_bf16(a[i], b2[j], acc2[i][j], 0, 0, 0);
            }
        slot = (slot == 2) ? 0 : slot + 1;
        nslot = (nslot == 2) ? 0 : nslot + 1;
    }

    constexpr int CB = FUSED ? 32 : 64;
    #pragma unroll
    for (int i = 0; i < 4; i++) {
        #pragma unroll
        for (int rr = 0; rr < 4; rr++) {
            int row = m0 + wr * 64 + i * 16 + quad * 4 + rr;
            if (row >= Mrows) continue;
            size_t orow = WL ? (size_t)(rowbase + row) : (size_t)row;
            float scl = 0.f;
            if (EPI == 2) scl = row_wgt[rowbase + row];
            #pragma unroll
            for (int j = 0; j < NJ; j++) {
                int n = n0 + wc * CB + j * 16 + l16;
                float v = acc1[i][j][rr];
                if (EPI == 0) {
                    float u = acc2[i][j][rr];
                    float h = v / (1.f + __expf(-v)) * u;
                    ((unsigned short*)Cout)[orow * N + n] = f2bf(h);
                } else if (EPI == 1) {
                    ((float*)Cout)[orow * N + n] = v;
                } else {
                    ((float*)Cout)[orow * N + n] = v * scl;
                }
            }
        }
    }
}

// ---------------- launch ----------------
extern "C" void kernel_launch(void* const* d_in, const int* in_sizes, int n_in,
                              void* d_out, int out_size, void* d_ws, size_t ws_size,
                              hipStream_t stream) {
    const float* x        = (const float*)d_in[0];
    const float* router_w = (const float*)d_in[1];
    const float* e_bias   = (const float*)d_in[2];
    const float* gate_w   = (const float*)d_in[3];
    const float* up_w     = (const float*)d_in[4];
    const float* down_w   = (const float*)d_in[5];
    const float* sh_gate  = (const float*)d_in[6];
    const float* sh_up    = (const float*)d_in[7];
    const float* sh_down  = (const float*)d_in[8];
    float* out = (float*)d_out;
    char* ws = (char*)d_ws;

    int*   counts    = (int*)(ws);
    int*   base      = (int*)(ws + 256);
    int*   cursor    = (int*)(ws + 512);
    int*   topk_idx  = (int*)(ws + 1024);
    float* topk_w    = (float*)(ws + 1024 + 131072);
    int*   row_token = (int*)(ws + 1024 + 2 * 131072);
    float* row_wgt   = (float*)(ws + 1024 + 3 * 131072);
    float* scoresbuf = (float*)(ws + 1024 + 4 * 131072);           // 1 MB
    int*   pos_of    = (int*)(ws + 1664 * 1024);                   // 128 KB
    int*   tile_e    = (int*)(ws + 1800 * 1024);                   // 1.25 KB
    int*   tile_m0   = (int*)(ws + 1808 * 1024);                   // 1.25 KB
    const size_t MB = 1u << 20;
    unsigned short* xb        = (unsigned short*)(ws + 2 * MB);    // 8 MB
    unsigned short* Hs        = (unsigned short*)(ws + 10 * MB);   // 16 MB
    unsigned short* Hr        = (unsigned short*)(ws + 26 * MB);   // 32 MB
    unsigned short* sh_gate_t = (unsigned short*)(ws + 58 * MB);   // 4 MB
    unsigned short* sh_up_t   = (unsigned short*)(ws + 62 * MB);   // 4 MB
    unsigned short* sh_down_t = (unsigned short*)(ws + 66 * MB);   // 4 MB
    unsigned short* gate_t    = (unsigned short*)(ws + 70 * MB);   // 64 MB
    unsigned short* up_t      = (unsigned short*)(ws + 134 * MB);  // 64 MB
    unsigned short* down_t    = (unsigned short*)(ws + 198 * MB);  // 64 MB -> 262 MB
    // O overlays gate_t+up_t (dead after routed fused GEMM): 32768x1024 f32 = 128 MiB
    float* O = (float*)(ws + 70 * MB);

    // ---- routing ----
    router_scores_k<<<S_TOK / 32, 256, 0, stream>>>(x, router_w, scoresbuf, counts);
    topk_k<<<S_TOK / 4, 256, 0, stream>>>(scoresbuf, e_bias, topk_idx, topk_w, counts);
    scan_k<<<1, 64, 0, stream>>>(counts, base, cursor, tile_e, tile_m0);
    scatter_k<<<ROWS_TOTAL / 256, 256, 0, stream>>>(topk_idx, topk_w, cursor, row_token, row_wgt, pos_of);

    // ---- prepass: bf16 conversion + weight transposes (fast 4x4-register path) ----
    cvt_bf16_k<<<S_TOK * C_DIM / 8 / 256, 256, 0, stream>>>(x, xb, S_TOK * C_DIM / 8);
    transpose_k<<<dim3(HS_DIM / 64, C_DIM / 64, 1), 256, 0, stream>>>(sh_gate, sh_gate_t, C_DIM, HS_DIM);
    transpose_k<<<dim3(HS_DIM / 64, C_DIM / 64, 1), 256, 0, stream>>>(sh_up,   sh_up_t,   C_DIM, HS_DIM);
    transpose_k<<<dim3(C_DIM / 64, HS_DIM / 64, 1), 256, 0, stream>>>(sh_down, sh_down_t, HS_DIM, C_DIM);
    transpose_k<<<dim3(H_DIM / 64, C_DIM / 64, E_NUM), 256, 0, stream>>>(gate_w, gate_t, C_DIM, H_DIM);
    transpose_k<<<dim3(H_DIM / 64, C_DIM / 64, E_NUM), 256, 0, stream>>>(up_w,   up_t,   C_DIM, H_DIM);
    transpose_k<<<dim3(C_DIM / 64, H_DIM / 64, E_NUM), 256, 0, stream>>>(down_w, down_t, H_DIM, C_DIM);

    // ---- shared expert ----
    gemm2_k<true, false, false, 0><<<dim3(HS_DIM / 64, S_TOK / 128, 1), 256, 0, stream>>>(
        (const short*)xb, (const short*)sh_gate_t, (const short*)sh_up_t, Hs,
        S_TOK, HS_DIM, C_DIM, nullptr, nullptr, nullptr, nullptr, nullptr, nullptr);
    gemm2_k<false, false, false, 1><<<dim3(C_DIM / 128, S_TOK / 128, 1), 256, 0, stream>>>(
        (const short*)Hs, (const short*)sh_down_t, nullptr, out,
        S_TOK, C_DIM, HS_DIM, nullptr, nullptr, nullptr, nullptr, nullptr, nullptr);

    // ---- routed experts (worklist-balanced) ----
    gemm2_k<true, true, true, 0><<<dim3(H_DIM / 64, T_TILES, 1), 256, 0, stream>>>(
        (const short*)xb, (const short*)gate_t, (const short*)up_t, Hr,
        0, H_DIM, C_DIM, counts, base, row_token, row_wgt, tile_e, tile_m0);
    gemm2_k<false, false, true, 2><<<dim3(C_DIM / 128, T_TILES, 1), 256, 0, stream>>>(
        (const short*)Hr, (const short*)down_t, nullptr, O,
        0, C_DIM, H_DIM, counts, base, row_token, row_wgt, tile_e, tile_m0);

    // ---- combine routed into out (out already holds shared-expert result) ----
    combine_k<<<S_TOK, 256, 0, stream>>>(O, pos_of, out);
}